// Round 11
// baseline (806.731 us; speedup 1.0000x reference)
//
#include <hip/hip_runtime.h>
#include <hip/hip_bf16.h>
#include <math.h>

// ---------------------------------------------------------------------------
// Mamba2 layer (round 17): round-16 (verified 795us, reproducible ±0.2us)
// with ONE change: out_proj/w2 GEMMs back to BK=32 (measured 62.8-63.3us
// in rounds 0-2 vs 68.4-68.9us at BK=64 in rounds 3/16 — the BK=64 cost was
// hidden inside round-9's bundled changes). Everything else byte-identical.
// ---------------------------------------------------------------------------

namespace {
constexpr int BB = 8;
constexpr int S = 2048;
constexpr int DM = 512;
constexpr int DIP = 2320;
constexpr int DIPP = 2432;       // padded to 19*128
constexpr int DI = 1024;
constexpr int CDIM = 1280;
constexpr int NH = 16;
constexpr int HD = 64;
constexpr int DSTATE = 128;
constexpr int CH = 128;
constexpr int NC = S / CH;       // 16
constexpr int FF = 2048;
constexpr float EPS = 1e-5f;
constexpr int LP = 132;          // padded K stride for SSD LDS tiles
}

using bf16_t = __hip_bfloat16;
typedef __attribute__((ext_vector_type(8))) short short8;
typedef __attribute__((ext_vector_type(4))) float f32x4;

__device__ __forceinline__ float gelu_exact(float x) {
    return 0.5f * x * (1.0f + erff(x * 0.7071067811865476f));
}
__device__ __forceinline__ unsigned short f2bfu(float f) {
    bf16_t b = __float2bfloat16(f);
    return *(unsigned short*)&b;
}
__device__ __forceinline__ float bfu2f(unsigned short u) {
    union { unsigned int i; float f; } v; v.i = (unsigned)u << 16; return v.f;
}

__device__ __forceinline__ void block_sum2(float& a, float& b) {
    #pragma unroll
    for (int o = 32; o > 0; o >>= 1) {
        a += __shfl_down(a, o, 64);
        b += __shfl_down(b, o, 64);
    }
    __shared__ float sa[4], sb[4];
    int w = threadIdx.x >> 6;
    if ((threadIdx.x & 63) == 0) { sa[w] = a; sb[w] = b; }
    __syncthreads();
    a = sa[0] + sa[1] + sa[2] + sa[3];
    b = sb[0] + sb[1] + sb[2] + sb[3];
}

// ---------------------------------------------------------------------------
// bf16 MFMA GEMM, register-staged + LDS double-buffered, parametric BK.
// Register staging = T14 issue-early/write-late: global loads issued before
// the barrier stay in flight; the implied vmcnt wait sits at the ds_write
// after the MFMA cluster.
// ---------------------------------------------------------------------------
template <int BM, int BK, int ACT, bool HASBIAS, bool OUTBF>
__global__ __launch_bounds__(256)
void mfma_gemm(const bf16_t* __restrict__ A, const bf16_t* __restrict__ W,
               const float* __restrict__ bias, void* __restrict__ Cout,
               int N, int K, int lda, int ldw, int ldc,
               long batchA, long batchW, long batchC)
{
    A += (long)blockIdx.z * batchA;
    W += (long)blockIdx.z * batchW;
    constexpr int NJ = (BM == 128) ? 4 : 2;
    constexpr int KO = BK / 32;            // 32-wide k-subtiles per staged tile
    constexpr int QA = 256 / BM;           // octet stride between a thread's A loads
    constexpr int TA = (BM * BK) / 2048;   // A short8 loads per thread
    constexpr int TW = (128 * BK) / 2048;  // W short8 loads per thread
    __shared__ bf16_t As[2][BM * BK];
    __shared__ bf16_t Ws[2][128 * BK];
    const int tid = threadIdx.x;
    const int lane = tid & 63;
    const int wave = tid >> 6;
    const long bm = (long)blockIdx.y * BM;
    const int bn = blockIdx.x * 128;

    const int rA = tid & (BM - 1);
    const int qA = tid / BM;
    const int rW = tid & 127;
    const int qW = tid >> 7;
    const bf16_t* Ag = A + (bm + rA) * (long)lda + qA * 8;
    const bf16_t* Wg = W + ((long)bn + rW) * (long)ldw + qW * 8;
    const int laoff = (qA * BM + rA) * 8;
    const int lwoff = (qW * 128 + rW) * 8;

    const int kq = lane >> 4;
    const int lr = lane & 15;
    const int wm = (BM == 128) ? (wave & 1) * 64 : 0;
    const int wn = (BM == 128) ? (wave >> 1) * 64 : wave * 32;

    f32x4 acc[4][NJ];
    #pragma unroll
    for (int i = 0; i < 4; i++)
        #pragma unroll
        for (int j = 0; j < NJ; j++) acc[i][j] = (f32x4){0.f, 0.f, 0.f, 0.f};

    short8 ra[TA], rw[TW];
    #pragma unroll
    for (int u = 0; u < TA; u++) ra[u] = *(const short8*)(Ag + u * (QA * 8));
    #pragma unroll
    for (int u = 0; u < TW; u++) rw[u] = *(const short8*)(Wg + u * 16);
    #pragma unroll
    for (int u = 0; u < TA; u++) *(short8*)&As[0][laoff + u * (QA * BM * 8)] = ra[u];
    #pragma unroll
    for (int u = 0; u < TW; u++) *(short8*)&Ws[0][lwoff + u * 2048] = rw[u];

    const int nt = K / BK;
    for (int t = 0; t < nt; t++) {
        const int cur = t & 1, nxt = cur ^ 1;
        if (t + 1 < nt) {
            const long ko = (long)(t + 1) * BK;
            #pragma unroll
            for (int u = 0; u < TA; u++) ra[u] = *(const short8*)(Ag + ko + u * (QA * 8));
            #pragma unroll
            for (int u = 0; u < TW; u++) rw[u] = *(const short8*)(Wg + ko + u * 16);
        }
        __syncthreads();
        #pragma unroll
        for (int hk = 0; hk < KO; hk++) {
            short8 af[4], bfr[NJ];
            #pragma unroll
            for (int i = 0; i < 4; i++)
                af[i] = *(const short8*)&As[cur][((hk * 4 + kq) * BM + wm + i * 16 + lr) * 8];
            #pragma unroll
            for (int j = 0; j < NJ; j++)
                bfr[j] = *(const short8*)&Ws[cur][((hk * 4 + kq) * 128 + wn + j * 16 + lr) * 8];
            #pragma unroll
            for (int i = 0; i < 4; i++)
                #pragma unroll
                for (int j = 0; j < NJ; j++)
                    acc[i][j] = __builtin_amdgcn_mfma_f32_16x16x32_bf16(af[i], bfr[j], acc[i][j], 0, 0, 0);
        }
        if (t + 1 < nt) {
            #pragma unroll
            for (int u = 0; u < TA; u++) *(short8*)&As[nxt][laoff + u * (QA * BM * 8)] = ra[u];
            #pragma unroll
            for (int u = 0; u < TW; u++) *(short8*)&Ws[nxt][lwoff + u * 2048] = rw[u];
        }
    }

    #pragma unroll
    for (int i = 0; i < 4; i++) {
        #pragma unroll
        for (int j = 0; j < NJ; j++) {
            int col = bn + wn + j * 16 + lr;
            if (col < N) {
                float bv = HASBIAS ? bias[col] : 0.f;
                #pragma unroll
                for (int r = 0; r < 4; r++) {
                    long row = bm + wm + i * 16 + kq * 4 + r;
                    float v = acc[i][j][r] + bv;
                    if (ACT == 1) v = gelu_exact(v);
                    if (OUTBF) ((bf16_t*)Cout)[row * (long)ldc + col + blockIdx.z * batchC] = __float2bfloat16(v);
                    else       ((float*)Cout)[row * (long)ldc + col + blockIdx.z * batchC] = v;
                }
            }
        }
    }
}

// ---------------------------------------------------------------------------
// Fused: tgt f32 -> tgt_bf (bf16 copy) AND dt = softplus(tgt @ Wdt^T + bias).
// ---------------------------------------------------------------------------
__global__ __launch_bounds__(256)
void dt_cvt(const float* __restrict__ tgt, const float* __restrict__ Wdt,
            const float* __restrict__ dt_bias, bf16_t* __restrict__ tgt_bf,
            float* __restrict__ dts)
{
    const int lane = threadIdx.x & 63;
    const int wave = threadIdx.x >> 6;
    float Wl[16][8];
    #pragma unroll
    for (int h = 0; h < 16; h++) {
        float4 a = *(const float4*)&Wdt[h * 512 + lane * 8];
        float4 b = *(const float4*)&Wdt[h * 512 + lane * 8 + 4];
        Wl[h][0] = a.x; Wl[h][1] = a.y; Wl[h][2] = a.z; Wl[h][3] = a.w;
        Wl[h][4] = b.x; Wl[h][5] = b.y; Wl[h][6] = b.z; Wl[h][7] = b.w;
    }
    float bs[16];
    #pragma unroll
    for (int h = 0; h < 16; h++) bs[h] = dt_bias[h];

    const long row0 = ((long)blockIdx.x * 4 + wave) * 4;
    #pragma unroll
    for (int rr = 0; rr < 4; rr++) {
        const long t = row0 + rr;
        float4 xa = *(const float4*)&tgt[t * 512 + lane * 8];
        float4 xb = *(const float4*)&tgt[t * 512 + lane * 8 + 4];
        float x[8] = {xa.x, xa.y, xa.z, xa.w, xb.x, xb.y, xb.z, xb.w};
        short8 ob;
        #pragma unroll
        for (int q = 0; q < 8; q++) ob[q] = (short)f2bfu(x[q]);
        *(short8*)&tgt_bf[t * 512 + lane * 8] = ob;

        float acc[16];
        #pragma unroll
        for (int h = 0; h < 16; h++) {
            float s = 0.f;
            #pragma unroll
            for (int q = 0; q < 8; q++) s += x[q] * Wl[h][q];
            acc[h] = s;
        }
        #pragma unroll
        for (int off = 32; off > 0; off >>= 1)
            #pragma unroll
            for (int h = 0; h < 16; h++)
                acc[h] += __shfl_xor(acc[h], off, 64);
        if (lane == 0) {
            #pragma unroll
            for (int h = 0; h < 16; h++) {
                float v = acc[h] + bs[h];
                dts[t * NH + h] = (v > 20.f) ? v : log1pf(__expf(v));
            }
        }
    }
}

// ---------------------------------------------------------------------------
__global__ __launch_bounds__(256)
void cvt_bf16(const float* __restrict__ s, bf16_t* __restrict__ d, long n)
{
    long i = ((long)blockIdx.x * 256 + threadIdx.x) * 4;
    if (i >= n) return;
    float4 v = *(const float4*)(s + i);
    d[i + 0] = __float2bfloat16(v.x);
    d[i + 1] = __float2bfloat16(v.y);
    d[i + 2] = __float2bfloat16(v.z);
    d[i + 3] = __float2bfloat16(v.w);
}

__global__ __launch_bounds__(256)
void cvt_bf16_pad(const float* __restrict__ s, bf16_t* __restrict__ d,
                  int rows_src, long total, int cols)
{
    long i = (long)blockIdx.x * 256 + threadIdx.x;
    if (i >= total) return;
    long r = i / cols;
    d[i] = __float2bfloat16(r < rows_src ? s[i] : 0.f);
}

// ---------------------------------------------------------------------------
// Causal depthwise conv (width 4) + SiLU, register rolling-window.
// ---------------------------------------------------------------------------
__global__ __launch_bounds__(256)
void conv_silu_t16(const bf16_t* __restrict__ zx, const float* __restrict__ cw,
                   const float* __restrict__ cb, bf16_t* __restrict__ xBC)
{
    const int quad = blockIdx.x * 64 + (threadIdx.x & 63);   // 0..319
    const int wv = threadIdx.x >> 6;
    const int c = quad * 4;
    const int s0 = blockIdx.y * 64 + wv * 16;
    const long t0 = (long)blockIdx.z * S + s0;

    float wgt[4][4];
    #pragma unroll
    for (int cc = 0; cc < 4; cc++)
        #pragma unroll
        for (int k = 0; k < 4; k++) wgt[cc][k] = cw[(c + cc) * 4 + k];
    float bias[4];
    #pragma unroll
    for (int cc = 0; cc < 4; cc++) bias[cc] = cb[c + cc];

    unsigned long long rows[19];
    #pragma unroll
    for (int i = 0; i < 19; i++) {
        int s = s0 + i - 3;
        rows[i] = (s >= 0) ? *(const unsigned long long*)&zx[(t0 + i - 3) * DIP + DI + c] : 0ULL;
    }
    #pragma unroll
    for (int i = 0; i < 16; i++) {
        float v[4];
        #pragma unroll
        for (int cc = 0; cc < 4; cc++) v[cc] = bias[cc];
        #pragma unroll
        for (int k = 0; k < 4; k++) {
            unsigned long long u = rows[i + k];
            v[0] += bfu2f((unsigned short)(u      )) * wgt[0][k];
            v[1] += bfu2f((unsigned short)(u >> 16)) * wgt[1][k];
            v[2] += bfu2f((unsigned short)(u >> 32)) * wgt[2][k];
            v[3] += bfu2f((unsigned short)(u >> 48)) * wgt[3][k];
        }
        unsigned long long o = 0;
        #pragma unroll
        for (int cc = 0; cc < 4; cc++) {
            float sv = v[cc] / (1.f + __expf(-v[cc]));
            o |= (unsigned long long)f2bfu(sv) << (16 * cc);
        }
        *(unsigned long long*)&xBC[(t0 + i) * (long)CDIM + c] = o;
    }
}

// ---------------------------------------------------------------------------
// SSD states (MFMA), split in n-halves: block = (b,c,h,nh).
// ---------------------------------------------------------------------------
__global__ __launch_bounds__(256)
void ssd_states(const bf16_t* __restrict__ xBC, const float* __restrict__ dts,
                const float* __restrict__ A_log,
                float* __restrict__ st, float* __restrict__ acs_all,
                float* __restrict__ cdlog)
{
    const int bid = blockIdx.x;
    const int nh = bid & 1;
    const int h = (bid >> 1) & 15;
    const int c = (bid >> 5) & 15;
    const int b = bid >> 9;
    const int sbid = (b * NC + c) * NH + h;
    const int tid = threadIdx.x;
    const int lane = tid & 63;
    const int wave = tid >> 6;
    __shared__ float dtv[128];
    __shared__ float acs[128];
    __shared__ float wj[128];
    __shared__ bf16_t XT[64 * LP];
    __shared__ bf16_t BwT[64 * LP];
    const long t0 = (long)b * S + (long)c * CH;
    const float Ah = -__expf(A_log[h]);

    if (tid < 128) {
        float d = dts[(t0 + tid) * NH + h];
        dtv[tid] = d;
        acs[tid] = d * Ah;
    }
    __syncthreads();
    for (int off = 1; off < 128; off <<= 1) {
        float add = 0.f;
        if (tid < 128 && tid >= off) add = acs[tid - off];
        __syncthreads();
        if (tid < 128 && tid >= off) acs[tid] += add;
        __syncthreads();
    }
    const float el = acs[127];
    if (tid < 128) wj[tid] = __expf(el - acs[tid]) * dtv[tid];
    if (nh == 0) {
        if (tid < 128) acs_all[(long)sbid * 128 + tid] = acs[tid];
        if (tid == 0) cdlog[sbid] = el;
    }
    __syncthreads();

    const int n0b = nh * 64;
    for (int i = tid; i < 4096; i += 256) {
        int p = i & 63, jp = (i >> 6) << 1;
        unsigned short a = *(const unsigned short*)&xBC[(t0 + jp) * CDIM + h * HD + p];
        unsigned short bb = *(const unsigned short*)&xBC[(t0 + jp + 1) * CDIM + h * HD + p];
        *(unsigned int*)&XT[p * LP + jp] = (unsigned)a | ((unsigned)bb << 16);
    }
    for (int i = tid; i < 4096; i += 256) {
        int n = i & 63, jp = (i >> 6) << 1;
        float v0 = __bfloat162float(xBC[(t0 + jp) * CDIM + DI + n0b + n]) * wj[jp];
        float v1 = __bfloat162float(xBC[(t0 + jp + 1) * CDIM + DI + n0b + n]) * wj[jp + 1];
        *(unsigned int*)&BwT[n * LP + jp] = (unsigned)f2bfu(v0) | ((unsigned)f2bfu(v1) << 16);
    }
    __syncthreads();

    const int kq = lane >> 4;
    const int lr = lane & 15;
    const int p0w = (wave & 1) * 32;
    const int n0w = (wave >> 1) * 32;
    f32x4 acc[2][2];
    #pragma unroll
    for (int i = 0; i < 2; i++)
        #pragma unroll
        for (int j = 0; j < 2; j++) acc[i][j] = (f32x4){0.f, 0.f, 0.f, 0.f};
    #pragma unroll
    for (int t = 0; t < 4; t++) {
        short8 af[2], bfr[2];
        #pragma unroll
        for (int i = 0; i < 2; i++)
            af[i] = *(const short8*)&XT[(p0w + i * 16 + lr) * LP + t * 32 + kq * 8];
        #pragma unroll
        for (int j = 0; j < 2; j++)
            bfr[j] = *(const short8*)&BwT[(n0w + j * 16 + lr) * LP + t * 32 + kq * 8];
        #pragma unroll
        for (int i = 0; i < 2; i++)
            #pragma unroll
            for (int j = 0; j < 2; j++)
                acc[i][j] = __builtin_amdgcn_mfma_f32_16x16x32_bf16(af[i], bfr[j], acc[i][j], 0, 0, 0);
    }
    long base = (long)sbid * 8192;
    #pragma unroll
    for (int i = 0; i < 2; i++)
        #pragma unroll
        for (int j = 0; j < 2; j++) {
            int col = n0b + n0w + j * 16 + lr;
            #pragma unroll
            for (int r = 0; r < 4; r++) {
                int p = p0w + i * 16 + kq * 4 + r;
                st[base + p * 128 + col] = acc[i][j][r];
            }
        }
}

// ---------------------------------------------------------------------------
// Chunk-state scan; emits prev (state at chunk start) as bf16 directly.
// ---------------------------------------------------------------------------
__global__ __launch_bounds__(256)
void ssd_scan(const float* __restrict__ st, const float* __restrict__ cdlog,
              bf16_t* __restrict__ prevb)
{
    const int h = blockIdx.x & 15;
    const int b = blockIdx.x >> 4;
    const int q0 = blockIdx.y * 8;
    const int tid = threadIdx.x;
    float prev[8];
    #pragma unroll
    for (int q = 0; q < 8; q++) prev[q] = 0.f;
    for (int c = 0; c < NC; c++) {
        int bc = (b * NC + c) * NH + h;
        float cd = __expf(cdlog[bc]);
        long base = (long)bc * 8192 + (long)q0 * 256;
        #pragma unroll
        for (int q = 0; q < 8; q++) {
            long idx = base + (long)q * 256 + tid;
            float v = st[idx];
            prevb[idx] = __float2bfloat16(prev[q]);
            prev[q] = cd * prev[q] + v;
        }
    }
}

// ---------------------------------------------------------------------------
// SSD output (MFMA, fused diag+off+D*x), split in i-halves.
// ---------------------------------------------------------------------------
__global__ __launch_bounds__(256)
void ssd_out(const bf16_t* __restrict__ xBC, const float* __restrict__ dts,
             const bf16_t* __restrict__ G, const bf16_t* __restrict__ prevb,
             const float* __restrict__ acs_all, const float* __restrict__ D_head,
             bf16_t* __restrict__ y)
{
    const int bid = blockIdx.x;
    const int ih = bid & 1;
    const int h = (bid >> 1) & 15;
    const int c = (bid >> 5) & 15;
    const int b = bid >> 9;
    const int sbid = (b * NC + c) * NH + h;
    const int tid = threadIdx.x;
    const int lane = tid & 63;
    const int wave = tid >> 6;
    __shared__ float dtv[128];
    __shared__ float acs[128];
    __shared__ float eacs[64];
    __shared__ bf16_t Abuf[64 * LP];
    __shared__ bf16_t Bbuf[64 * LP];
    const long t0 = (long)b * S + (long)c * CH;
    const int m0b = ih * 64;

    if (tid < 128) {
        dtv[tid] = dts[(t0 + tid) * NH + h];
        acs[tid] = acs_all[(long)sbid * 128 + tid];
    }
    __syncthreads();
    if (tid < 64) eacs[tid] = __expf(acs[m0b + tid]);

    const bf16_t* Gb = G + (long)(b * NC + c) * 128 * 128;
    for (int i = tid; i < 4096; i += 256) {
        int rl = i >> 6, kp = (i & 63) << 1;
        int grow = m0b + rl;
        unsigned int g2 = *(const unsigned int*)&Gb[grow * 128 + kp];
        float w0 = (kp     <= grow) ? bfu2f((unsigned short)(g2      )) * __expf(acs[grow] - acs[kp    ]) * dtv[kp    ] : 0.f;
        float w1 = (kp + 1 <= grow) ? bfu2f((unsigned short)(g2 >> 16)) * __expf(acs[grow] - acs[kp + 1]) * dtv[kp + 1] : 0.f;
        *(unsigned int*)&Abuf[rl * LP + kp] = (unsigned)f2bfu(w0) | ((unsigned)f2bfu(w1) << 16);
    }
    for (int i = tid; i < 4096; i += 256) {
        int p = i & 63, jp = (i >> 6) << 1;
        unsigned short a = *(const unsigned short*)&xBC[(t0 + jp) * CDIM + h * HD + p];
        unsigned short bb = *(const unsigned short*)&xBC[(t0 + jp + 1) * CDIM + h * HD + p];
        *(unsigned int*)&Bbuf[p * LP + jp] = (unsigned)a | ((unsigned)bb << 16);
    }
    __syncthreads();

    const int kq = lane >> 4;
    const int lr = lane & 15;
    const int m0w = (wave & 1) * 32;
    const int p0 = (wave >> 1) * 32;
    f32x4 acc[2][2];
    #pragma unroll
    for (int i = 0; i < 2; i++)
        #pragma unroll
        for (int j = 0; j < 2; j++) acc[i][j] = (f32x4){0.f, 0.f, 0.f, 0.f};

    #pragma unroll
    for (int t = 0; t < 4; t++) {
        short8 af[2], bfr[2];
        #pragma unroll
        for (int i = 0; i < 2; i++)
            af[i] = *(const short8*)&Abuf[(m0w + i * 16 + lr) * LP + t * 32 + kq * 8];
        #pragma unroll
        for (int j = 0; j < 2; j++)
            bfr[j] = *(const short8*)&Bbuf[(p0 + j * 16 + lr) * LP + t * 32 + kq * 8];
        #pragma unroll
        for (int i = 0; i < 2; i++)
            #pragma unroll
            for (int j = 0; j < 2; j++)
                acc[i][j] = __builtin_amdgcn_mfma_f32_16x16x32_bf16(af[i], bfr[j], acc[i][j], 0, 0, 0);
    }
    const float Dh = D_head[h];
    float dx[2][2][4];
    #pragma unroll
    for (int i = 0; i < 2; i++)
        #pragma unroll
        for (int j = 0; j < 2; j++) {
            int col = p0 + j * 16 + lr;
            #pragma unroll
            for (int r = 0; r < 4; r++) {
                int rl = m0w + i * 16 + kq * 4 + r;
                dx[i][j][r] = Dh * __bfloat162float(Bbuf[col * LP + m0b + rl]);
            }
        }
    __syncthreads();

    for (int i = tid; i < 4096; i += 256) {
        int rl = i >> 6, np = (i & 63) << 1;
        unsigned int c2 = *(const unsigned int*)&xBC[(t0 + m0b + rl) * CDIM + DI + DSTATE + np];
        float e = eacs[rl];
        float v0 = e * bfu2f((unsigned short)(c2      ));
        float v1 = e * bfu2f((unsigned short)(c2 >> 16));
        *(unsigned int*)&Abuf[rl * LP + np] = (unsigned)f2bfu(v0) | ((unsigned)f2bfu(v1) << 16);
    }
    for (int i = tid; i < 4096; i += 256) {
        int p = i >> 6, np = (i & 63) << 1;
        *(unsigned int*)&Bbuf[p * LP + np] =
            *(const unsigned int*)&prevb[(long)sbid * 8192 + p * 128 + np];
    }
    __syncthreads();

    #pragma unroll
    for (int t = 0; t < 4; t++) {
        short8 af[2], bfr[2];
        #pragma unroll
        for (int i = 0; i < 2; i++)
            af[i] = *(const short8*)&Abuf[(m0w + i * 16 + lr) * LP + t * 32 + kq * 8];
        #pragma unroll
        for (int j = 0; j < 2; j++)
            bfr[j] = *(const short8*)&Bbuf[(p0 + j * 16 + lr) * LP + t * 32 + kq * 8];
        #pragma unroll
        for (int i = 0; i < 2; i++)
            #pragma unroll
            for (int j = 0; j < 2; j++)
                acc[i][j] = __builtin_amdgcn_mfma_f32_16x16x32_bf16(af[i], bfr[j], acc[i][j], 0, 0, 0);
    }

    #pragma unroll
    for (int i = 0; i < 2; i++)
        #pragma unroll
        for (int j = 0; j < 2; j++) {
            int col = p0 + j * 16 + lr;
            #pragma unroll
            for (int r = 0; r < 4; r++) {
                int rl = m0w + i * 16 + kq * 4 + r;
                y[(t0 + m0b + rl) * DI + h * HD + col] = __float2bfloat16(acc[i][j][r] + dx[i][j][r]);
            }
        }
}

// ---------------------------------------------------------------------------
// Gated RMSNorm, 8B/lane vector loads: thread owns 4 consecutive elements.
// ---------------------------------------------------------------------------
__global__ __launch_bounds__(256)
void gated_rms(const bf16_t* __restrict__ y, const bf16_t* __restrict__ zx,
               const float* __restrict__ norm_w, bf16_t* __restrict__ yn)
{
    const long t = blockIdx.x;
    const int d = threadIdx.x * 4;
    unsigned long long zu = *(const unsigned long long*)&zx[t * DIP + d];
    unsigned long long yu = *(const unsigned long long*)&y[t * DI + d];
    float g[4];
    float ss = 0.f, dummy = 0.f;
    #pragma unroll
    for (int q = 0; q < 4; q++) {
        float zv = bfu2f((unsigned short)(zu >> (16 * q)));
        float yv = bfu2f((unsigned short)(yu >> (16 * q)));
        float gv = yv * (zv / (1.f + __expf(-zv)));
        g[q] = gv;
        ss += gv * gv;
    }
    block_sum2(ss, dummy);
    float scale = rsqrtf(ss * (1.f / DI) + EPS);
    unsigned long long o = 0;
    #pragma unroll
    for (int q = 0; q < 4; q++)
        o |= (unsigned long long)f2bfu(g[q] * scale * norm_w[d + q]) << (16 * q);
    *(unsigned long long*)&yn[t * DI + d] = o;
}

// ---------------------------------------------------------------------------
// out = LayerNorm(x + r); 2 rows/block. W16: also bf16 copy.
// ---------------------------------------------------------------------------
template <bool W16>
__global__ __launch_bounds__(256)
void add_ln(const float* __restrict__ x, const float* __restrict__ r,
            const float* __restrict__ w, const float* __restrict__ bpar,
            float* __restrict__ o32, bf16_t* __restrict__ o16)
{
    const int tid = threadIdx.x;
    const long t = blockIdx.x * 2 + (tid >> 7);
    const int i = (tid & 127) * 4;
    float4 xv = *(const float4*)(x + t * DM + i);
    float4 rv = *(const float4*)(r + t * DM + i);
    float v[4] = {xv.x + rv.x, xv.y + rv.y, xv.z + rv.z, xv.w + rv.w};
    float s = v[0] + v[1] + v[2] + v[3];
    float s2 = v[0]*v[0] + v[1]*v[1] + v[2]*v[2] + v[3]*v[3];
    #pragma unroll
    for (int o = 32; o > 0; o >>= 1) {
        s += __shfl_down(s, o, 64);
        s2 += __shfl_down(s2, o, 64);
    }
    __shared__ float sa[4], sb[4];
    int wv = tid >> 6;
    if ((tid & 63) == 0) { sa[wv] = s; sb[wv] = s2; }
    __syncthreads();
    int base = (tid >> 7) * 2;
    s = sa[base] + sa[base + 1];
    s2 = sb[base] + sb[base + 1];
    float mean = s * (1.f / DM);
    float var = s2 * (1.f / DM) - mean * mean;
    float inv = rsqrtf(var + EPS);
    float4 ov;
    float* op = (float*)&ov;
    unsigned long long o16u = 0;
    #pragma unroll
    for (int q = 0; q < 4; q++) {
        float o = (v[q] - mean) * inv * w[i + q] + bpar[i + q];
        op[q] = o;
        if (W16) o16u |= (unsigned long long)f2bfu(o) << (16 * q);
    }
    *(float4*)(o32 + t * DM + i) = ov;
    if (W16) *(unsigned long long*)&o16[t * DM + i] = o16u;
}

// ---------------------------------------------------------------------------

extern "C" void kernel_launch(void* const* d_in, const int* in_sizes, int n_in,
                              void* d_out, int out_size, void* d_ws, size_t ws_size,
                              hipStream_t stream)
{
    const float* tgt       = (const float*)d_in[0];
    const float* in_proj_w = (const float*)d_in[5];
    const float* conv_w    = (const float*)d_in[6];
    const float* conv_b    = (const float*)d_in[7];
    const float* dt_bias   = (const float*)d_in[8];
    const float* A_log     = (const float*)d_in[9];
    const float* D_head    = (const float*)d_in[10];
    const float* norm_w    = (const float*)d_in[11];
    const float* out_proj_w= (const float*)d_in[12];
    const float* norm1_w   = (const float*)d_in[13];
    const float* norm1_b   = (const float*)d_in[14];
    const float* w1        = (const float*)d_in[15];
    const float* b1        = (const float*)d_in[16];
    const float* w2        = (const float*)d_in[17];
    const float* b2        = (const float*)d_in[18];
    const float* norm3_w   = (const float*)d_in[19];
    const float* norm3_b   = (const float*)d_in[20];
    float* out = (float*)d_out;

    float* ws = (float*)d_ws;

    const size_t SZ_INW  = (size_t)DIPP * DM / 2;
    const size_t SZ_OUTW = (size_t)DM * DI / 2;
    const size_t SZ_W1   = (size_t)FF * DM / 2;
    const size_t SZ_W2   = (size_t)DM * FF / 2;
    size_t wo = 0;
    bf16_t* inW  = (bf16_t*)(ws + wo); wo += SZ_INW;
    bf16_t* outW = (bf16_t*)(ws + wo); wo += SZ_OUTW;
    bf16_t* w1b  = (bf16_t*)(ws + wo); wo += SZ_W1;
    bf16_t* w2b  = (bf16_t*)(ws + wo); wo += SZ_W2;
    const size_t WB = wo;

    const size_t PB = (size_t)S * DM / 2            // tgt_bf
                    + (size_t)S * DIP / 2           // zx_bf
                    + (size_t)S * NH                // dts
                    + (size_t)S * CDIM / 2          // xBC_bf
                    + (size_t)NC * 128 * 128 / 2    // G (bf16)
                    + (size_t)NC * NH * 128         // acs
                    + (size_t)NC * NH               // cdl
                    + (size_t)S * DI                // y region (ybf | prevb)
                    + (size_t)S * DI;               // st
    int NB = 0;
    for (int nb = 8; nb >= 1; nb >>= 1) {
        if (ws_size >= (WB + (size_t)nb * PB) * sizeof(float)) { NB = nb; break; }
    }
    if (NB == 0) return;

    {
        long n = (long)DIPP * DM;
        cvt_bf16_pad<<<(n + 255) / 256, 256, 0, stream>>>(in_proj_w, inW, DIP, n, DM);
        n = (long)DM * DI;
        cvt_bf16<<<(n / 4 + 255) / 256, 256, 0, stream>>>(out_proj_w, outW, n);
        n = (long)FF * DM;
        cvt_bf16<<<(n / 4 + 255) / 256, 256, 0, stream>>>(w1, w1b, n);
        n = (long)DM * FF;
        cvt_bf16<<<(n / 4 + 255) / 256, 256, 0, stream>>>(w2, w2b, n);
    }

    for (int b0 = 0; b0 < BB; b0 += NB) {
        const long Tg = (long)NB * S;
        size_t o = WB;
        bf16_t* tgt_bf = (bf16_t*)(ws + o); o += (size_t)Tg * DM / 2;
        bf16_t* zx     = (bf16_t*)(ws + o); o += (size_t)Tg * DIP / 2;
        float*  dts    = ws + o;            o += (size_t)Tg * NH;
        bf16_t* xBC    = (bf16_t*)(ws + o); o += (size_t)Tg * CDIM / 2;
        bf16_t* Gbuf   = (bf16_t*)(ws + o); o += (size_t)NB * NC * 128 * 128 / 2;
        float*  acs    = ws + o;            o += (size_t)NB * NC * NH * 128;
        float*  cdl    = ws + o;            o += (size_t)NB * NC * NH;
        float*  ybuf   = ws + o;            o += (size_t)Tg * DI;
        float*  st     = ws + o;            o += (size_t)Tg * DI;

        bf16_t* ybf   = (bf16_t*)ybuf;                         // first half of ybuf
        bf16_t* prevb = (bf16_t*)(ybuf + (size_t)Tg * DI / 2); // second half of ybuf
        bf16_t* yn  = (bf16_t*)st;
        float*  t2  = ybuf;
        float*  tb  = (float*)zx;
        bf16_t* tbb = (bf16_t*)(((float*)zx) + Tg * DM);
        bf16_t* h1  = (bf16_t*)ybuf;
        float*  fb  = (float*)xBC;

        const float* tgt_g = tgt + (long)b0 * S * DM;
        float* out_g = out + (long)b0 * S * DM;

        // fused: tgt -> bf16 copy + dt = softplus(tgt @ Wdt^T + dt_bias)
        dt_cvt<<<Tg / 16, 256, 0, stream>>>(
            tgt_g, in_proj_w + (long)(DI + CDIM) * DM, dt_bias, tgt_bf, dts);
        mfma_gemm<128, 32, 0, false, true><<<dim3(DIPP / 128, Tg / 128, 1), 256, 0, stream>>>(
            tgt_bf, inW, nullptr, zx, DIP, DM, DM, DM, DIP, 0, 0, 0);
        conv_silu_t16<<<dim3(CDIM / 256, S / 64, NB), 256, 0, stream>>>(zx, conv_w, conv_b, xBC);
        mfma_gemm<128, 32, 0, false, true><<<dim3(1, 1, NB * NC), 256, 0, stream>>>(
            xBC + DI + DSTATE, xBC + DI, nullptr, Gbuf,
            128, DSTATE, CDIM, CDIM, 128,
            (long)CH * CDIM, (long)CH * CDIM, (long)128 * 128);
        ssd_states<<<NB * NC * NH * 2, 256, 0, stream>>>(xBC, dts, A_log, st, acs, cdl);
        ssd_scan<<<dim3(NB * NH, 4), 256, 0, stream>>>(st, cdl, prevb);
        ssd_out<<<NB * NC * NH * 2, 256, 0, stream>>>(xBC, dts, Gbuf, prevb, acs, D_head, ybf);
        gated_rms<<<Tg, 256, 0, stream>>>(ybf, zx, norm_w, yn);
        mfma_gemm<128, 32, 0, false, false><<<dim3(DM / 128, Tg / 128, 1), 256, 0, stream>>>(
            yn, outW, nullptr, t2, DM, DI, DI, DI, DM, 0, 0, 0);
        add_ln<true><<<Tg / 2, 256, 0, stream>>>(tgt_g, t2, norm1_w, norm1_b, tb, tbb);
        mfma_gemm<128, 32, 1, true, true><<<dim3(FF / 128, Tg / 128, 1), 256, 0, stream>>>(
            tbb, w1b, b1, h1, FF, DM, DM, DM, FF, 0, 0, 0);
        mfma_gemm<128, 32, 0, true, false><<<dim3(DM / 128, Tg / 128, 1), 256, 0, stream>>>(
            h1, w2b, b2, fb, DM, FF, FF, FF, DM, 0, 0, 0);
        add_ln<false><<<Tg / 2, 256, 0, stream>>>(tb, fb, norm3_w, norm3_b, out_g, nullptr);
    }
}

// Round 12
// 791.880 us; speedup vs baseline: 1.0188x; 1.0188x over previous
//
#include <hip/hip_runtime.h>
#include <hip/hip_bf16.h>
#include <math.h>

// ---------------------------------------------------------------------------
// Mamba2 layer (round 18 = FINAL: byte-identical resubmit of the verified
// best configuration, measured 795.02 / 795.18 us across two containers).
//
// Configuration ledger (11 measured rounds):
//  - GEMM: single-depth register-staged + LDS double-buffer, 256 thr, BM=128.
//    BK=32 for in_proj/G/w1; BK=64 for out_proj/w2 (BK=32 twins: +11us total,
//    round 17; depth-2: twins faster but total +29us, round 14; split-K: null,
//    rounds 10/11; gload_lds: +60us, round 7; SSD-merge: +56us, round 15).
//  - dt projection fused with tgt bf16 cvt (dt_cvt): win (round 9).
//  - ssd_scan emits bf16 prev directly: win (round 9).
//  - Remaining gap to aggregate roofline is the serial 13-dispatch structure
//    (each shape caps occupancy ~20%); per-kernel wins are repriced by
//    L3-residency coupling between dispatches.
// ---------------------------------------------------------------------------

namespace {
constexpr int BB = 8;
constexpr int S = 2048;
constexpr int DM = 512;
constexpr int DIP = 2320;
constexpr int DIPP = 2432;       // padded to 19*128
constexpr int DI = 1024;
constexpr int CDIM = 1280;
constexpr int NH = 16;
constexpr int HD = 64;
constexpr int DSTATE = 128;
constexpr int CH = 128;
constexpr int NC = S / CH;       // 16
constexpr int FF = 2048;
constexpr float EPS = 1e-5f;
constexpr int LP = 132;          // padded K stride for SSD LDS tiles
}

using bf16_t = __hip_bfloat16;
typedef __attribute__((ext_vector_type(8))) short short8;
typedef __attribute__((ext_vector_type(4))) float f32x4;

__device__ __forceinline__ float gelu_exact(float x) {
    return 0.5f * x * (1.0f + erff(x * 0.7071067811865476f));
}
__device__ __forceinline__ unsigned short f2bfu(float f) {
    bf16_t b = __float2bfloat16(f);
    return *(unsigned short*)&b;
}
__device__ __forceinline__ float bfu2f(unsigned short u) {
    union { unsigned int i; float f; } v; v.i = (unsigned)u << 16; return v.f;
}

__device__ __forceinline__ void block_sum2(float& a, float& b) {
    #pragma unroll
    for (int o = 32; o > 0; o >>= 1) {
        a += __shfl_down(a, o, 64);
        b += __shfl_down(b, o, 64);
    }
    __shared__ float sa[4], sb[4];
    int w = threadIdx.x >> 6;
    if ((threadIdx.x & 63) == 0) { sa[w] = a; sb[w] = b; }
    __syncthreads();
    a = sa[0] + sa[1] + sa[2] + sa[3];
    b = sb[0] + sb[1] + sb[2] + sb[3];
}

// ---------------------------------------------------------------------------
// bf16 MFMA GEMM, register-staged + LDS double-buffered, parametric BK.
// Register staging = T14 issue-early/write-late: global loads issued before
// the barrier stay in flight; the implied vmcnt wait sits at the ds_write
// after the MFMA cluster.
// ---------------------------------------------------------------------------
template <int BM, int BK, int ACT, bool HASBIAS, bool OUTBF>
__global__ __launch_bounds__(256)
void mfma_gemm(const bf16_t* __restrict__ A, const bf16_t* __restrict__ W,
               const float* __restrict__ bias, void* __restrict__ Cout,
               int N, int K, int lda, int ldw, int ldc,
               long batchA, long batchW, long batchC)
{
    A += (long)blockIdx.z * batchA;
    W += (long)blockIdx.z * batchW;
    constexpr int NJ = (BM == 128) ? 4 : 2;
    constexpr int KO = BK / 32;            // 32-wide k-subtiles per staged tile
    constexpr int QA = 256 / BM;           // octet stride between a thread's A loads
    constexpr int TA = (BM * BK) / 2048;   // A short8 loads per thread
    constexpr int TW = (128 * BK) / 2048;  // W short8 loads per thread
    __shared__ bf16_t As[2][BM * BK];
    __shared__ bf16_t Ws[2][128 * BK];
    const int tid = threadIdx.x;
    const int lane = tid & 63;
    const int wave = tid >> 6;
    const long bm = (long)blockIdx.y * BM;
    const int bn = blockIdx.x * 128;

    const int rA = tid & (BM - 1);
    const int qA = tid / BM;
    const int rW = tid & 127;
    const int qW = tid >> 7;
    const bf16_t* Ag = A + (bm + rA) * (long)lda + qA * 8;
    const bf16_t* Wg = W + ((long)bn + rW) * (long)ldw + qW * 8;
    const int laoff = (qA * BM + rA) * 8;
    const int lwoff = (qW * 128 + rW) * 8;

    const int kq = lane >> 4;
    const int lr = lane & 15;
    const int wm = (BM == 128) ? (wave & 1) * 64 : 0;
    const int wn = (BM == 128) ? (wave >> 1) * 64 : wave * 32;

    f32x4 acc[4][NJ];
    #pragma unroll
    for (int i = 0; i < 4; i++)
        #pragma unroll
        for (int j = 0; j < NJ; j++) acc[i][j] = (f32x4){0.f, 0.f, 0.f, 0.f};

    short8 ra[TA], rw[TW];
    #pragma unroll
    for (int u = 0; u < TA; u++) ra[u] = *(const short8*)(Ag + u * (QA * 8));
    #pragma unroll
    for (int u = 0; u < TW; u++) rw[u] = *(const short8*)(Wg + u * 16);
    #pragma unroll
    for (int u = 0; u < TA; u++) *(short8*)&As[0][laoff + u * (QA * BM * 8)] = ra[u];
    #pragma unroll
    for (int u = 0; u < TW; u++) *(short8*)&Ws[0][lwoff + u * 2048] = rw[u];

    const int nt = K / BK;
    for (int t = 0; t < nt; t++) {
        const int cur = t & 1, nxt = cur ^ 1;
        if (t + 1 < nt) {
            const long ko = (long)(t + 1) * BK;
            #pragma unroll
            for (int u = 0; u < TA; u++) ra[u] = *(const short8*)(Ag + ko + u * (QA * 8));
            #pragma unroll
            for (int u = 0; u < TW; u++) rw[u] = *(const short8*)(Wg + ko + u * 16);
        }
        __syncthreads();
        #pragma unroll
        for (int hk = 0; hk < KO; hk++) {
            short8 af[4], bfr[NJ];
            #pragma unroll
            for (int i = 0; i < 4; i++)
                af[i] = *(const short8*)&As[cur][((hk * 4 + kq) * BM + wm + i * 16 + lr) * 8];
            #pragma unroll
            for (int j = 0; j < NJ; j++)
                bfr[j] = *(const short8*)&Ws[cur][((hk * 4 + kq) * 128 + wn + j * 16 + lr) * 8];
            #pragma unroll
            for (int i = 0; i < 4; i++)
                #pragma unroll
                for (int j = 0; j < NJ; j++)
                    acc[i][j] = __builtin_amdgcn_mfma_f32_16x16x32_bf16(af[i], bfr[j], acc[i][j], 0, 0, 0);
        }
        if (t + 1 < nt) {
            #pragma unroll
            for (int u = 0; u < TA; u++) *(short8*)&As[nxt][laoff + u * (QA * BM * 8)] = ra[u];
            #pragma unroll
            for (int u = 0; u < TW; u++) *(short8*)&Ws[nxt][lwoff + u * 2048] = rw[u];
        }
    }

    #pragma unroll
    for (int i = 0; i < 4; i++) {
        #pragma unroll
        for (int j = 0; j < NJ; j++) {
            int col = bn + wn + j * 16 + lr;
            if (col < N) {
                float bv = HASBIAS ? bias[col] : 0.f;
                #pragma unroll
                for (int r = 0; r < 4; r++) {
                    long row = bm + wm + i * 16 + kq * 4 + r;
                    float v = acc[i][j][r] + bv;
                    if (ACT == 1) v = gelu_exact(v);
                    if (OUTBF) ((bf16_t*)Cout)[row * (long)ldc + col + blockIdx.z * batchC] = __float2bfloat16(v);
                    else       ((float*)Cout)[row * (long)ldc + col + blockIdx.z * batchC] = v;
                }
            }
        }
    }
}

// ---------------------------------------------------------------------------
// Fused: tgt f32 -> tgt_bf (bf16 copy) AND dt = softplus(tgt @ Wdt^T + bias).
// ---------------------------------------------------------------------------
__global__ __launch_bounds__(256)
void dt_cvt(const float* __restrict__ tgt, const float* __restrict__ Wdt,
            const float* __restrict__ dt_bias, bf16_t* __restrict__ tgt_bf,
            float* __restrict__ dts)
{
    const int lane = threadIdx.x & 63;
    const int wave = threadIdx.x >> 6;
    float Wl[16][8];
    #pragma unroll
    for (int h = 0; h < 16; h++) {
        float4 a = *(const float4*)&Wdt[h * 512 + lane * 8];
        float4 b = *(const float4*)&Wdt[h * 512 + lane * 8 + 4];
        Wl[h][0] = a.x; Wl[h][1] = a.y; Wl[h][2] = a.z; Wl[h][3] = a.w;
        Wl[h][4] = b.x; Wl[h][5] = b.y; Wl[h][6] = b.z; Wl[h][7] = b.w;
    }
    float bs[16];
    #pragma unroll
    for (int h = 0; h < 16; h++) bs[h] = dt_bias[h];

    const long row0 = ((long)blockIdx.x * 4 + wave) * 4;
    #pragma unroll
    for (int rr = 0; rr < 4; rr++) {
        const long t = row0 + rr;
        float4 xa = *(const float4*)&tgt[t * 512 + lane * 8];
        float4 xb = *(const float4*)&tgt[t * 512 + lane * 8 + 4];
        float x[8] = {xa.x, xa.y, xa.z, xa.w, xb.x, xb.y, xb.z, xb.w};
        short8 ob;
        #pragma unroll
        for (int q = 0; q < 8; q++) ob[q] = (short)f2bfu(x[q]);
        *(short8*)&tgt_bf[t * 512 + lane * 8] = ob;

        float acc[16];
        #pragma unroll
        for (int h = 0; h < 16; h++) {
            float s = 0.f;
            #pragma unroll
            for (int q = 0; q < 8; q++) s += x[q] * Wl[h][q];
            acc[h] = s;
        }
        #pragma unroll
        for (int off = 32; off > 0; off >>= 1)
            #pragma unroll
            for (int h = 0; h < 16; h++)
                acc[h] += __shfl_xor(acc[h], off, 64);
        if (lane == 0) {
            #pragma unroll
            for (int h = 0; h < 16; h++) {
                float v = acc[h] + bs[h];
                dts[t * NH + h] = (v > 20.f) ? v : log1pf(__expf(v));
            }
        }
    }
}

// ---------------------------------------------------------------------------
__global__ __launch_bounds__(256)
void cvt_bf16(const float* __restrict__ s, bf16_t* __restrict__ d, long n)
{
    long i = ((long)blockIdx.x * 256 + threadIdx.x) * 4;
    if (i >= n) return;
    float4 v = *(const float4*)(s + i);
    d[i + 0] = __float2bfloat16(v.x);
    d[i + 1] = __float2bfloat16(v.y);
    d[i + 2] = __float2bfloat16(v.z);
    d[i + 3] = __float2bfloat16(v.w);
}

__global__ __launch_bounds__(256)
void cvt_bf16_pad(const float* __restrict__ s, bf16_t* __restrict__ d,
                  int rows_src, long total, int cols)
{
    long i = (long)blockIdx.x * 256 + threadIdx.x;
    if (i >= total) return;
    long r = i / cols;
    d[i] = __float2bfloat16(r < rows_src ? s[i] : 0.f);
}

// ---------------------------------------------------------------------------
// Causal depthwise conv (width 4) + SiLU, register rolling-window.
// ---------------------------------------------------------------------------
__global__ __launch_bounds__(256)
void conv_silu_t16(const bf16_t* __restrict__ zx, const float* __restrict__ cw,
                   const float* __restrict__ cb, bf16_t* __restrict__ xBC)
{
    const int quad = blockIdx.x * 64 + (threadIdx.x & 63);   // 0..319
    const int wv = threadIdx.x >> 6;
    const int c = quad * 4;
    const int s0 = blockIdx.y * 64 + wv * 16;
    const long t0 = (long)blockIdx.z * S + s0;

    float wgt[4][4];
    #pragma unroll
    for (int cc = 0; cc < 4; cc++)
        #pragma unroll
        for (int k = 0; k < 4; k++) wgt[cc][k] = cw[(c + cc) * 4 + k];
    float bias[4];
    #pragma unroll
    for (int cc = 0; cc < 4; cc++) bias[cc] = cb[c + cc];

    unsigned long long rows[19];
    #pragma unroll
    for (int i = 0; i < 19; i++) {
        int s = s0 + i - 3;
        rows[i] = (s >= 0) ? *(const unsigned long long*)&zx[(t0 + i - 3) * DIP + DI + c] : 0ULL;
    }
    #pragma unroll
    for (int i = 0; i < 16; i++) {
        float v[4];
        #pragma unroll
        for (int cc = 0; cc < 4; cc++) v[cc] = bias[cc];
        #pragma unroll
        for (int k = 0; k < 4; k++) {
            unsigned long long u = rows[i + k];
            v[0] += bfu2f((unsigned short)(u      )) * wgt[0][k];
            v[1] += bfu2f((unsigned short)(u >> 16)) * wgt[1][k];
            v[2] += bfu2f((unsigned short)(u >> 32)) * wgt[2][k];
            v[3] += bfu2f((unsigned short)(u >> 48)) * wgt[3][k];
        }
        unsigned long long o = 0;
        #pragma unroll
        for (int cc = 0; cc < 4; cc++) {
            float sv = v[cc] / (1.f + __expf(-v[cc]));
            o |= (unsigned long long)f2bfu(sv) << (16 * cc);
        }
        *(unsigned long long*)&xBC[(t0 + i) * (long)CDIM + c] = o;
    }
}

// ---------------------------------------------------------------------------
// SSD states (MFMA), split in n-halves: block = (b,c,h,nh).
// ---------------------------------------------------------------------------
__global__ __launch_bounds__(256)
void ssd_states(const bf16_t* __restrict__ xBC, const float* __restrict__ dts,
                const float* __restrict__ A_log,
                float* __restrict__ st, float* __restrict__ acs_all,
                float* __restrict__ cdlog)
{
    const int bid = blockIdx.x;
    const int nh = bid & 1;
    const int h = (bid >> 1) & 15;
    const int c = (bid >> 5) & 15;
    const int b = bid >> 9;
    const int sbid = (b * NC + c) * NH + h;
    const int tid = threadIdx.x;
    const int lane = tid & 63;
    const int wave = tid >> 6;
    __shared__ float dtv[128];
    __shared__ float acs[128];
    __shared__ float wj[128];
    __shared__ bf16_t XT[64 * LP];
    __shared__ bf16_t BwT[64 * LP];
    const long t0 = (long)b * S + (long)c * CH;
    const float Ah = -__expf(A_log[h]);

    if (tid < 128) {
        float d = dts[(t0 + tid) * NH + h];
        dtv[tid] = d;
        acs[tid] = d * Ah;
    }
    __syncthreads();
    for (int off = 1; off < 128; off <<= 1) {
        float add = 0.f;
        if (tid < 128 && tid >= off) add = acs[tid - off];
        __syncthreads();
        if (tid < 128 && tid >= off) acs[tid] += add;
        __syncthreads();
    }
    const float el = acs[127];
    if (tid < 128) wj[tid] = __expf(el - acs[tid]) * dtv[tid];
    if (nh == 0) {
        if (tid < 128) acs_all[(long)sbid * 128 + tid] = acs[tid];
        if (tid == 0) cdlog[sbid] = el;
    }
    __syncthreads();

    const int n0b = nh * 64;
    for (int i = tid; i < 4096; i += 256) {
        int p = i & 63, jp = (i >> 6) << 1;
        unsigned short a = *(const unsigned short*)&xBC[(t0 + jp) * CDIM + h * HD + p];
        unsigned short bb = *(const unsigned short*)&xBC[(t0 + jp + 1) * CDIM + h * HD + p];
        *(unsigned int*)&XT[p * LP + jp] = (unsigned)a | ((unsigned)bb << 16);
    }
    for (int i = tid; i < 4096; i += 256) {
        int n = i & 63, jp = (i >> 6) << 1;
        float v0 = __bfloat162float(xBC[(t0 + jp) * CDIM + DI + n0b + n]) * wj[jp];
        float v1 = __bfloat162float(xBC[(t0 + jp + 1) * CDIM + DI + n0b + n]) * wj[jp + 1];
        *(unsigned int*)&BwT[n * LP + jp] = (unsigned)f2bfu(v0) | ((unsigned)f2bfu(v1) << 16);
    }
    __syncthreads();

    const int kq = lane >> 4;
    const int lr = lane & 15;
    const int p0w = (wave & 1) * 32;
    const int n0w = (wave >> 1) * 32;
    f32x4 acc[2][2];
    #pragma unroll
    for (int i = 0; i < 2; i++)
        #pragma unroll
        for (int j = 0; j < 2; j++) acc[i][j] = (f32x4){0.f, 0.f, 0.f, 0.f};
    #pragma unroll
    for (int t = 0; t < 4; t++) {
        short8 af[2], bfr[2];
        #pragma unroll
        for (int i = 0; i < 2; i++)
            af[i] = *(const short8*)&XT[(p0w + i * 16 + lr) * LP + t * 32 + kq * 8];
        #pragma unroll
        for (int j = 0; j < 2; j++)
            bfr[j] = *(const short8*)&BwT[(n0w + j * 16 + lr) * LP + t * 32 + kq * 8];
        #pragma unroll
        for (int i = 0; i < 2; i++)
            #pragma unroll
            for (int j = 0; j < 2; j++)
                acc[i][j] = __builtin_amdgcn_mfma_f32_16x16x32_bf16(af[i], bfr[j], acc[i][j], 0, 0, 0);
    }
    long base = (long)sbid * 8192;
    #pragma unroll
    for (int i = 0; i < 2; i++)
        #pragma unroll
        for (int j = 0; j < 2; j++) {
            int col = n0b + n0w + j * 16 + lr;
            #pragma unroll
            for (int r = 0; r < 4; r++) {
                int p = p0w + i * 16 + kq * 4 + r;
                st[base + p * 128 + col] = acc[i][j][r];
            }
        }
}

// ---------------------------------------------------------------------------
// Chunk-state scan; emits prev (state at chunk start) as bf16 directly.
// ---------------------------------------------------------------------------
__global__ __launch_bounds__(256)
void ssd_scan(const float* __restrict__ st, const float* __restrict__ cdlog,
              bf16_t* __restrict__ prevb)
{
    const int h = blockIdx.x & 15;
    const int b = blockIdx.x >> 4;
    const int q0 = blockIdx.y * 8;
    const int tid = threadIdx.x;
    float prev[8];
    #pragma unroll
    for (int q = 0; q < 8; q++) prev[q] = 0.f;
    for (int c = 0; c < NC; c++) {
        int bc = (b * NC + c) * NH + h;
        float cd = __expf(cdlog[bc]);
        long base = (long)bc * 8192 + (long)q0 * 256;
        #pragma unroll
        for (int q = 0; q < 8; q++) {
            long idx = base + (long)q * 256 + tid;
            float v = st[idx];
            prevb[idx] = __float2bfloat16(prev[q]);
            prev[q] = cd * prev[q] + v;
        }
    }
}

// ---------------------------------------------------------------------------
// SSD output (MFMA, fused diag+off+D*x), split in i-halves.
// ---------------------------------------------------------------------------
__global__ __launch_bounds__(256)
void ssd_out(const bf16_t* __restrict__ xBC, const float* __restrict__ dts,
             const bf16_t* __restrict__ G, const bf16_t* __restrict__ prevb,
             const float* __restrict__ acs_all, const float* __restrict__ D_head,
             bf16_t* __restrict__ y)
{
    const int bid = blockIdx.x;
    const int ih = bid & 1;
    const int h = (bid >> 1) & 15;
    const int c = (bid >> 5) & 15;
    const int b = bid >> 9;
    const int sbid = (b * NC + c) * NH + h;
    const int tid = threadIdx.x;
    const int lane = tid & 63;
    const int wave = tid >> 6;
    __shared__ float dtv[128];
    __shared__ float acs[128];
    __shared__ float eacs[64];
    __shared__ bf16_t Abuf[64 * LP];
    __shared__ bf16_t Bbuf[64 * LP];
    const long t0 = (long)b * S + (long)c * CH;
    const int m0b = ih * 64;

    if (tid < 128) {
        dtv[tid] = dts[(t0 + tid) * NH + h];
        acs[tid] = acs_all[(long)sbid * 128 + tid];
    }
    __syncthreads();
    if (tid < 64) eacs[tid] = __expf(acs[m0b + tid]);

    const bf16_t* Gb = G + (long)(b * NC + c) * 128 * 128;
    for (int i = tid; i < 4096; i += 256) {
        int rl = i >> 6, kp = (i & 63) << 1;
        int grow = m0b + rl;
        unsigned int g2 = *(const unsigned int*)&Gb[grow * 128 + kp];
        float w0 = (kp     <= grow) ? bfu2f((unsigned short)(g2      )) * __expf(acs[grow] - acs[kp    ]) * dtv[kp    ] : 0.f;
        float w1 = (kp + 1 <= grow) ? bfu2f((unsigned short)(g2 >> 16)) * __expf(acs[grow] - acs[kp + 1]) * dtv[kp + 1] : 0.f;
        *(unsigned int*)&Abuf[rl * LP + kp] = (unsigned)f2bfu(w0) | ((unsigned)f2bfu(w1) << 16);
    }
    for (int i = tid; i < 4096; i += 256) {
        int p = i & 63, jp = (i >> 6) << 1;
        unsigned short a = *(const unsigned short*)&xBC[(t0 + jp) * CDIM + h * HD + p];
        unsigned short bb = *(const unsigned short*)&xBC[(t0 + jp + 1) * CDIM + h * HD + p];
        *(unsigned int*)&Bbuf[p * LP + jp] = (unsigned)a | ((unsigned)bb << 16);
    }
    __syncthreads();

    const int kq = lane >> 4;
    const int lr = lane & 15;
    const int m0w = (wave & 1) * 32;
    const int p0 = (wave >> 1) * 32;
    f32x4 acc[2][2];
    #pragma unroll
    for (int i = 0; i < 2; i++)
        #pragma unroll
        for (int j = 0; j < 2; j++) acc[i][j] = (f32x4){0.f, 0.f, 0.f, 0.f};

    #pragma unroll
    for (int t = 0; t < 4; t++) {
        short8 af[2], bfr[2];
        #pragma unroll
        for (int i = 0; i < 2; i++)
            af[i] = *(const short8*)&Abuf[(m0w + i * 16 + lr) * LP + t * 32 + kq * 8];
        #pragma unroll
        for (int j = 0; j < 2; j++)
            bfr[j] = *(const short8*)&Bbuf[(p0 + j * 16 + lr) * LP + t * 32 + kq * 8];
        #pragma unroll
        for (int i = 0; i < 2; i++)
            #pragma unroll
            for (int j = 0; j < 2; j++)
                acc[i][j] = __builtin_amdgcn_mfma_f32_16x16x32_bf16(af[i], bfr[j], acc[i][j], 0, 0, 0);
    }
    const float Dh = D_head[h];
    float dx[2][2][4];
    #pragma unroll
    for (int i = 0; i < 2; i++)
        #pragma unroll
        for (int j = 0; j < 2; j++) {
            int col = p0 + j * 16 + lr;
            #pragma unroll
            for (int r = 0; r < 4; r++) {
                int rl = m0w + i * 16 + kq * 4 + r;
                dx[i][j][r] = Dh * __bfloat162float(Bbuf[col * LP + m0b + rl]);
            }
        }
    __syncthreads();

    for (int i = tid; i < 4096; i += 256) {
        int rl = i >> 6, np = (i & 63) << 1;
        unsigned int c2 = *(const unsigned int*)&xBC[(t0 + m0b + rl) * CDIM + DI + DSTATE + np];
        float e = eacs[rl];
        float v0 = e * bfu2f((unsigned short)(c2      ));
        float v1 = e * bfu2f((unsigned short)(c2 >> 16));
        *(unsigned int*)&Abuf[rl * LP + np] = (unsigned)f2bfu(v0) | ((unsigned)f2bfu(v1) << 16);
    }
    for (int i = tid; i < 4096; i += 256) {
        int p = i >> 6, np = (i & 63) << 1;
        *(unsigned int*)&Bbuf[p * LP + np] =
            *(const unsigned int*)&prevb[(long)sbid * 8192 + p * 128 + np];
    }
    __syncthreads();

    #pragma unroll
    for (int t = 0; t < 4; t++) {
        short8 af[2], bfr[2];
        #pragma unroll
        for (int i = 0; i < 2; i++)
            af[i] = *(const short8*)&Abuf[(m0w + i * 16 + lr) * LP + t * 32 + kq * 8];
        #pragma unroll
        for (int j = 0; j < 2; j++)
            bfr[j] = *(const short8*)&Bbuf[(p0 + j * 16 + lr) * LP + t * 32 + kq * 8];
        #pragma unroll
        for (int i = 0; i < 2; i++)
            #pragma unroll
            for (int j = 0; j < 2; j++)
                acc[i][j] = __builtin_amdgcn_mfma_f32_16x16x32_bf16(af[i], bfr[j], acc[i][j], 0, 0, 0);
    }

    #pragma unroll
    for (int i = 0; i < 2; i++)
        #pragma unroll
        for (int j = 0; j < 2; j++) {
            int col = p0 + j * 16 + lr;
            #pragma unroll
            for (int r = 0; r < 4; r++) {
                int rl = m0w + i * 16 + kq * 4 + r;
                y[(t0 + m0b + rl) * DI + h * HD + col] = __float2bfloat16(acc[i][j][r] + dx[i][j][r]);
            }
        }
}

// ---------------------------------------------------------------------------
// Gated RMSNorm, 8B/lane vector loads: thread owns 4 consecutive elements.
// ---------------------------------------------------------------------------
__global__ __launch_bounds__(256)
void gated_rms(const bf16_t* __restrict__ y, const bf16_t* __restrict__ zx,
               const float* __restrict__ norm_w, bf16_t* __restrict__ yn)
{
    const long t = blockIdx.x;
    const int d = threadIdx.x * 4;
    unsigned long long zu = *(const unsigned long long*)&zx[t * DIP + d];
    unsigned long long yu = *(const unsigned long long*)&y[t * DI + d];
    float g[4];
    float ss = 0.f, dummy = 0.f;
    #pragma unroll
    for (int q = 0; q < 4; q++) {
        float zv = bfu2f((unsigned short)(zu >> (16 * q)));
        float yv = bfu2f((unsigned short)(yu >> (16 * q)));
        float gv = yv * (zv / (1.f + __expf(-zv)));
        g[q] = gv;
        ss += gv * gv;
    }
    block_sum2(ss, dummy);
    float scale = rsqrtf(ss * (1.f / DI) + EPS);
    unsigned long long o = 0;
    #pragma unroll
    for (int q = 0; q < 4; q++)
        o |= (unsigned long long)f2bfu(g[q] * scale * norm_w[d + q]) << (16 * q);
    *(unsigned long long*)&yn[t * DI + d] = o;
}

// ---------------------------------------------------------------------------
// out = LayerNorm(x + r); 2 rows/block. W16: also bf16 copy.
// ---------------------------------------------------------------------------
template <bool W16>
__global__ __launch_bounds__(256)
void add_ln(const float* __restrict__ x, const float* __restrict__ r,
            const float* __restrict__ w, const float* __restrict__ bpar,
            float* __restrict__ o32, bf16_t* __restrict__ o16)
{
    const int tid = threadIdx.x;
    const long t = blockIdx.x * 2 + (tid >> 7);
    const int i = (tid & 127) * 4;
    float4 xv = *(const float4*)(x + t * DM + i);
    float4 rv = *(const float4*)(r + t * DM + i);
    float v[4] = {xv.x + rv.x, xv.y + rv.y, xv.z + rv.z, xv.w + rv.w};
    float s = v[0] + v[1] + v[2] + v[3];
    float s2 = v[0]*v[0] + v[1]*v[1] + v[2]*v[2] + v[3]*v[3];
    #pragma unroll
    for (int o = 32; o > 0; o >>= 1) {
        s += __shfl_down(s, o, 64);
        s2 += __shfl_down(s2, o, 64);
    }
    __shared__ float sa[4], sb[4];
    int wv = tid >> 6;
    if ((tid & 63) == 0) { sa[wv] = s; sb[wv] = s2; }
    __syncthreads();
    int base = (tid >> 7) * 2;
    s = sa[base] + sa[base + 1];
    s2 = sb[base] + sb[base + 1];
    float mean = s * (1.f / DM);
    float var = s2 * (1.f / DM) - mean * mean;
    float inv = rsqrtf(var + EPS);
    float4 ov;
    float* op = (float*)&ov;
    unsigned long long o16u = 0;
    #pragma unroll
    for (int q = 0; q < 4; q++) {
        float o = (v[q] - mean) * inv * w[i + q] + bpar[i + q];
        op[q] = o;
        if (W16) o16u |= (unsigned long long)f2bfu(o) << (16 * q);
    }
    *(float4*)(o32 + t * DM + i) = ov;
    if (W16) *(unsigned long long*)&o16[t * DM + i] = o16u;
}

// ---------------------------------------------------------------------------

extern "C" void kernel_launch(void* const* d_in, const int* in_sizes, int n_in,
                              void* d_out, int out_size, void* d_ws, size_t ws_size,
                              hipStream_t stream)
{
    const float* tgt       = (const float*)d_in[0];
    const float* in_proj_w = (const float*)d_in[5];
    const float* conv_w    = (const float*)d_in[6];
    const float* conv_b    = (const float*)d_in[7];
    const float* dt_bias   = (const float*)d_in[8];
    const float* A_log     = (const float*)d_in[9];
    const float* D_head    = (const float*)d_in[10];
    const float* norm_w    = (const float*)d_in[11];
    const float* out_proj_w= (const float*)d_in[12];
    const float* norm1_w   = (const float*)d_in[13];
    const float* norm1_b   = (const float*)d_in[14];
    const float* w1        = (const float*)d_in[15];
    const float* b1        = (const float*)d_in[16];
    const float* w2        = (const float*)d_in[17];
    const float* b2        = (const float*)d_in[18];
    const float* norm3_w   = (const float*)d_in[19];
    const float* norm3_b   = (const float*)d_in[20];
    float* out = (float*)d_out;

    float* ws = (float*)d_ws;

    const size_t SZ_INW  = (size_t)DIPP * DM / 2;
    const size_t SZ_OUTW = (size_t)DM * DI / 2;
    const size_t SZ_W1   = (size_t)FF * DM / 2;
    const size_t SZ_W2   = (size_t)DM * FF / 2;
    size_t wo = 0;
    bf16_t* inW  = (bf16_t*)(ws + wo); wo += SZ_INW;
    bf16_t* outW = (bf16_t*)(ws + wo); wo += SZ_OUTW;
    bf16_t* w1b  = (bf16_t*)(ws + wo); wo += SZ_W1;
    bf16_t* w2b  = (bf16_t*)(ws + wo); wo += SZ_W2;
    const size_t WB = wo;

    const size_t PB = (size_t)S * DM / 2            // tgt_bf
                    + (size_t)S * DIP / 2           // zx_bf
                    + (size_t)S * NH                // dts
                    + (size_t)S * CDIM / 2          // xBC_bf
                    + (size_t)NC * 128 * 128 / 2    // G (bf16)
                    + (size_t)NC * NH * 128         // acs
                    + (size_t)NC * NH               // cdl
                    + (size_t)S * DI                // y region (ybf | prevb)
                    + (size_t)S * DI;               // st
    int NB = 0;
    for (int nb = 8; nb >= 1; nb >>= 1) {
        if (ws_size >= (WB + (size_t)nb * PB) * sizeof(float)) { NB = nb; break; }
    }
    if (NB == 0) return;

    {
        long n = (long)DIPP * DM;
        cvt_bf16_pad<<<(n + 255) / 256, 256, 0, stream>>>(in_proj_w, inW, DIP, n, DM);
        n = (long)DM * DI;
        cvt_bf16<<<(n / 4 + 255) / 256, 256, 0, stream>>>(out_proj_w, outW, n);
        n = (long)FF * DM;
        cvt_bf16<<<(n / 4 + 255) / 256, 256, 0, stream>>>(w1, w1b, n);
        n = (long)DM * FF;
        cvt_bf16<<<(n / 4 + 255) / 256, 256, 0, stream>>>(w2, w2b, n);
    }

    for (int b0 = 0; b0 < BB; b0 += NB) {
        const long Tg = (long)NB * S;
        size_t o = WB;
        bf16_t* tgt_bf = (bf16_t*)(ws + o); o += (size_t)Tg * DM / 2;
        bf16_t* zx     = (bf16_t*)(ws + o); o += (size_t)Tg * DIP / 2;
        float*  dts    = ws + o;            o += (size_t)Tg * NH;
        bf16_t* xBC    = (bf16_t*)(ws + o); o += (size_t)Tg * CDIM / 2;
        bf16_t* Gbuf   = (bf16_t*)(ws + o); o += (size_t)NB * NC * 128 * 128 / 2;
        float*  acs    = ws + o;            o += (size_t)NB * NC * NH * 128;
        float*  cdl    = ws + o;            o += (size_t)NB * NC * NH;
        float*  ybuf   = ws + o;            o += (size_t)Tg * DI;
        float*  st     = ws + o;            o += (size_t)Tg * DI;

        bf16_t* ybf   = (bf16_t*)ybuf;                         // first half of ybuf
        bf16_t* prevb = (bf16_t*)(ybuf + (size_t)Tg * DI / 2); // second half of ybuf
        bf16_t* yn  = (bf16_t*)st;
        float*  t2  = ybuf;
        float*  tb  = (float*)zx;
        bf16_t* tbb = (bf16_t*)(((float*)zx) + Tg * DM);
        bf16_t* h1  = (bf16_t*)ybuf;
        float*  fb  = (float*)xBC;

        const float* tgt_g = tgt + (long)b0 * S * DM;
        float* out_g = out + (long)b0 * S * DM;

        // fused: tgt -> bf16 copy + dt = softplus(tgt @ Wdt^T + dt_bias)
        dt_cvt<<<Tg / 16, 256, 0, stream>>>(
            tgt_g, in_proj_w + (long)(DI + CDIM) * DM, dt_bias, tgt_bf, dts);
        mfma_gemm<128, 32, 0, false, true><<<dim3(DIPP / 128, Tg / 128, 1), 256, 0, stream>>>(
            tgt_bf, inW, nullptr, zx, DIP, DM, DM, DM, DIP, 0, 0, 0);
        conv_silu_t16<<<dim3(CDIM / 256, S / 64, NB), 256, 0, stream>>>(zx, conv_w, conv_b, xBC);
        mfma_gemm<128, 32, 0, false, true><<<dim3(1, 1, NB * NC), 256, 0, stream>>>(
            xBC + DI + DSTATE, xBC + DI, nullptr, Gbuf,
            128, DSTATE, CDIM, CDIM, 128,
            (long)CH * CDIM, (long)CH * CDIM, (long)128 * 128);
        ssd_states<<<NB * NC * NH * 2, 256, 0, stream>>>(xBC, dts, A_log, st, acs, cdl);
        ssd_scan<<<dim3(NB * NH, 4), 256, 0, stream>>>(st, cdl, prevb);
        ssd_out<<<NB * NC * NH * 2, 256, 0, stream>>>(xBC, dts, Gbuf, prevb, acs, D_head, ybf);
        gated_rms<<<Tg, 256, 0, stream>>>(ybf, zx, norm_w, yn);
        mfma_gemm<128, 64, 0, false, false><<<dim3(DM / 128, Tg / 128, 1), 256, 0, stream>>>(
            yn, outW, nullptr, t2, DM, DI, DI, DI, DM, 0, 0, 0);
        add_ln<true><<<Tg / 2, 256, 0, stream>>>(tgt_g, t2, norm1_w, norm1_b, tb, tbb);
        mfma_gemm<128, 32, 1, true, true><<<dim3(FF / 128, Tg / 128, 1), 256, 0, stream>>>(
            tbb, w1b, b1, h1, FF, DM, DM, DM, FF, 0, 0, 0);
        mfma_gemm<128, 64, 0, true, false><<<dim3(DM / 128, Tg / 128, 1), 256, 0, stream>>>(
            h1, w2b, b2, fb, DM, FF, FF, FF, DM, 0, 0, 0);
        add_ln<false><<<Tg / 2, 256, 0, stream>>>(tb, fb, norm3_w, norm3_b, out_g, nullptr);
    }
}